// Round 6
// baseline (217.156 us; speedup 1.0000x reference)
//
#include <hip/hip_runtime.h>
#include <math.h>

#define OS    320      // oversampled grid (ceil(1.25*256))
#define IMN   256
#define NCOIL 8
#define PI_F  3.14159265358979f
#define BETA_F 10.955108f   // pi*sqrt((4.8*0.75)^2 - 0.8)
#define GSCALE 65536.0f     // fp16 grid scaling (applied at pass1 staging)
#define PPT   8             // interp points per thread (pipelined)

typedef _Float16 half8  __attribute__((ext_vector_type(8)));
typedef _Float16 half4  __attribute__((ext_vector_type(4)));
typedef _Float16 half2v __attribute__((ext_vector_type(2)));
typedef unsigned uint2v __attribute__((ext_vector_type(2)));
typedef unsigned uint4v __attribute__((ext_vector_type(4)));

// f32 acc += f32 w * f16 h.lo / h.hi  (v_fma_mix_f32: no separate cvt)
__device__ __forceinline__ void fmamix_lo(float& acc, float w, unsigned h) {
    asm("v_fma_mix_f32 %0, %1, %2, %0 op_sel_hi:[0,1,0]"
        : "+v"(acc) : "v"(w), "v"(h));
}
__device__ __forceinline__ void fmamix_hi(float& acc, float w, unsigned h) {
    asm("v_fma_mix_f32 %0, %1, %2, %0 op_sel:[0,1,0] op_sel_hi:[0,1,0]"
        : "+v"(acc) : "v"(w), "v"(h));
}

// ---- Kaiser-Bessel: exact A&S I0 polynomial (matches reference) ----
__device__ __forceinline__ float i0f(float x) {
    if (x < 3.75f) {
        float y = x * (1.0f / 3.75f); y *= y;
        return 1.0f + y*(3.5156229f + y*(3.0899424f + y*(1.2067492f
             + y*(0.2659732f + y*(0.0360768f + y*0.0045813f)))));
    } else {
        float t = 3.75f / x;
        float p = 0.39894228f + t*(0.01328592f + t*(0.00225319f + t*(-0.00157565f
              + t*(0.00916281f + t*(-0.02057706f + t*(0.02635537f + t*(-0.01647633f
              + t*0.00392377f)))))));
        return expf(x) * rsqrtf(x) * p;
    }
}

__device__ __forceinline__ float apod1(int i) {
    float idx = (float)(i - 128);
    float c = PI_F * 6.0f * idx * (1.0f / (float)OS);
    float a = sqrtf(BETA_F * BETA_F - c * c);
    float sh = 0.5f * (expf(a) - expf(-a));
    return a / sh;
}

// complex acc (AR,AI) += (xr,xi packed f16 in H) * (wr + i*wi)
#define CACC(AR, AI, H) { fmamix_lo(AR, wr, H); fmamix_hi(AR, mwi, H); \
                          fmamix_lo(AI, wi, H); fmamix_hi(AI, wr, H); }

// ---- K1: fused apod + pad + DFT along x.  Block = image row iy (0..255).
// LDS holds the apodized, GSCALE'd row as packed f16 (xr,xi) per coil.
// out: [kx][y][coil] float2  (carries GSCALE).
__global__ __launch_bounds__(320) void dft_pass1(const float* __restrict__ imr,
                                                 const float* __restrict__ imi,
                                                 float2* __restrict__ out) {
    __shared__ unsigned xs[IMN * NCOIL];   // 8 KB packed f16 pairs
    int iy = blockIdx.x;
    int t  = threadIdx.x;                  // kx
    if (t < IMN) {
        float ap = apod1(t) * GSCALE;
        int base = iy * IMN + t;
        #pragma unroll
        for (int b = 0; b < 8; ++b) {
            float xr = imr[b * (IMN * IMN) + base] * ap;   // coalesced
            float xi = imi[b * (IMN * IMN) + base] * ap;
            half2v hh; hh.x = (_Float16)xr; hh.y = (_Float16)xi;
            xs[t * 8 + b] = __builtin_bit_cast(unsigned, hh);
        }
    }
    __syncthreads();

    float ar[8], ai[8];
    #pragma unroll
    for (int b = 0; b < 8; ++b) { ar[b] = 0.f; ai[b] = 0.f; }
    float ang_t = (float)t * (-2.0f * PI_F / (float)OS);
    float wsr = cosf(ang_t), wsi = sinf(ang_t);
    int idx = (t * 192) % 320;             // (t*n) mod 320, n=(m+192)%320
    float wr = 1.f, wi = 0.f;
    const uint4v* xv = (const uint4v*)xs;
    #pragma unroll 16
    for (int m = 0; m < 256; ++m) {
        if ((m & 15) == 0) {               // exact twiddle refresh
            float ang = (float)idx * (-2.0f * PI_F / (float)OS);
            wr = cosf(ang); wi = sinf(ang);
        }
        uint4v pa = xv[2 * m], pb = xv[2 * m + 1];   // 2x ds_read_b128
        float mwi = -wi;
        CACC(ar[0], ai[0], pa.x) CACC(ar[1], ai[1], pa.y)
        CACC(ar[2], ai[2], pa.z) CACC(ar[3], ai[3], pa.w)
        CACC(ar[4], ai[4], pb.x) CACC(ar[5], ai[5], pb.y)
        CACC(ar[6], ai[6], pb.z) CACC(ar[7], ai[7], pb.w)
        float nwr = fmaf(wr, wsr, -wi * wsi);
        float nwi = fmaf(wr, wsi,  wi * wsr);
        wr = nwr; wi = nwi;
        idx += t; if (idx >= OS) idx -= OS;
    }
    float ay = apod1(iy) * (1.0f / 256.0f);   // y-apod + /sqrt(ny*nx)
    int y = iy + 192; if (y >= OS) y -= OS;
    float4* op = (float4*)(out + ((size_t)t * OS + y) * NCOIL);
    #pragma unroll
    for (int q = 0; q < 4; ++q)
        op[q] = make_float4(ar[2*q] * ay, ai[2*q] * ay,
                            ar[2*q+1] * ay, ai[2*q+1] * ay);
}

// ---- K2: DFT along y (f16-packed LDS staging); fp16 grid out, fftshift folded
__global__ __launch_bounds__(320) void dft_pass2(const float2* __restrict__ in,
                                                 half8* __restrict__ outg) {
    __shared__ unsigned xs[IMN * NCOIL];
    int kx = blockIdx.x;
    int t  = threadIdx.x;
    const float2* row = in + (size_t)kx * OS * NCOIL;
    for (int i = t; i < IMN * NCOIL; i += 320) {
        int m = i >> 3, b = i & 7;
        int n = m + 192; if (n >= OS) n -= OS;
        float2 v = row[n * NCOIL + b];
        half2v hh; hh.x = (_Float16)v.x; hh.y = (_Float16)v.y;
        xs[i] = __builtin_bit_cast(unsigned, hh);
    }
    __syncthreads();

    float ar[8], ai[8];
    #pragma unroll
    for (int b = 0; b < 8; ++b) { ar[b] = 0.f; ai[b] = 0.f; }
    float ang_t = (float)t * (-2.0f * PI_F / (float)OS);
    float wsr = cosf(ang_t), wsi = sinf(ang_t);
    int idx = (t * 192) % 320;
    float wr = 1.f, wi = 0.f;
    const uint4v* xv = (const uint4v*)xs;
    #pragma unroll 16
    for (int m = 0; m < 256; ++m) {
        if ((m & 15) == 0) {
            float ang = (float)idx * (-2.0f * PI_F / (float)OS);
            wr = cosf(ang); wi = sinf(ang);
        }
        uint4v pa = xv[2 * m], pb = xv[2 * m + 1];
        float mwi = -wi;
        CACC(ar[0], ai[0], pa.x) CACC(ar[1], ai[1], pa.y)
        CACC(ar[2], ai[2], pa.z) CACC(ar[3], ai[3], pa.w)
        CACC(ar[4], ai[4], pb.x) CACC(ar[5], ai[5], pb.y)
        CACC(ar[6], ai[6], pb.z) CACC(ar[7], ai[7], pb.w)
        float nwr = fmaf(wr, wsr, -wi * wsi);
        float nwi = fmaf(wr, wsi,  wi * wsr);
        wr = nwr; wi = nwi;
        idx += t; if (idx >= OS) idx -= OS;
    }
    int r = t + 160;  if (r >= OS) r -= OS;   // fftshift fold (rows)
    int c = kx + 160; if (c >= OS) c -= OS;   // fftshift fold (cols)
    half8 h0, h1;                              // GSCALE already folded in
    #pragma unroll
    for (int q = 0; q < 4; ++q) {
        h0[2*q]   = (_Float16)ar[q];
        h0[2*q+1] = (_Float16)ai[q];
        h1[2*q]   = (_Float16)ar[q+4];
        h1[2*q+1] = (_Float16)ai[q+4];
    }
    half8* gp = outg + ((size_t)r * OS + c) * 2;
    gp[0] = h0; gp[1] = h1;
}

// ---- K3: KB 6x6 gather; 8 lanes/point (4 coil-pairs x 2 tap-parities),
// PPT points per thread with a 2-stage pipeline (issue next gathers before
// consuming current), LDS weight-LUT instead of exact I0, fma_mix accumulate.
#define ISSUE(KIDX, TJ, H)                                                  \
  {                                                                         \
    int kk_ = (KIDX); if (kk_ >= K) kk_ = K - 1;                            \
    TJ = trj2[kk_];                                                         \
    float cy_ = TJ.x * 1.25f + 160.0f;                                      \
    float cx_ = TJ.y * 1.25f + 160.0f;                                      \
    int y0_ = (int)ceilf(cy_ - 3.0f);                                       \
    int x0_ = (int)ceilf(cx_ - 3.0f);                                       \
    int ro_[6], co_[6];                                                     \
    _Pragma("unroll")                                                       \
    for (int j_ = 0; j_ < 6; ++j_) {                                        \
      int yy_ = y0_ + j_; if (yy_ < 0) yy_ += OS; if (yy_ >= OS) yy_ -= OS; \
      ro_[j_] = yy_ * (OS * 4);                                             \
      int xx_ = x0_ + j_; if (xx_ < 0) xx_ += OS; if (xx_ >= OS) xx_ -= OS; \
      co_[j_] = xx_ * 4 + cp;                                               \
    }                                                                       \
    _Pragma("unroll")                                                       \
    for (int j_ = 0; j_ < 6; ++j_) {                                        \
      _Pragma("unroll")                                                     \
      for (int p_ = 0; p_ < 3; ++p_)                                        \
        H[j_ * 3 + p_] = g4[ro_[j_] + co_[2 * p_ + tp]];                    \
    }                                                                       \
  }

#define LUTW(DST, U)                                                        \
  {                                                                         \
    float t_ = fminf((U) * (U) * 1024.0f, 1023.0f);                         \
    int i_ = (int)t_;                                                       \
    float fr_ = t_ - (float)i_;                                             \
    float a_ = gtab[i_], b_ = gtab[i_ + 1];                                 \
    DST = fmaf(fr_, b_ - a_, a_);                                           \
  }

#define CONSUME(TJ, H, KIDX)                                                \
  {                                                                         \
    float cy_ = TJ.x * 1.25f + 160.0f;                                      \
    float cx_ = TJ.y * 1.25f + 160.0f;                                      \
    int y0_ = (int)ceilf(cy_ - 3.0f);                                       \
    int x0_ = (int)ceilf(cx_ - 3.0f);                                       \
    float argu_ = (c < 6) ? ((float)(y0_ + c) - cy_) * (1.0f / 3.0f)        \
                          : ((float)(x0_ + (c - 6)) - cx_) * (1.0f / 3.0f); \
    float argv_ = ((float)(x0_ + 2 + cp) - cx_) * (1.0f / 3.0f);            \
    float u_, v_;                                                           \
    LUTW(u_, argu_) LUTW(v_, argv_)                                         \
    int gb_ = (threadIdx.x & 63) & 56;                                      \
    float wy_[6], wx_[6];                                                   \
    wy_[0] = __shfl(u_, gb_ + 0); wy_[1] = __shfl(u_, gb_ + 1);             \
    wy_[2] = __shfl(u_, gb_ + 2); wy_[3] = __shfl(u_, gb_ + 3);             \
    wy_[4] = __shfl(u_, gb_ + 4); wy_[5] = __shfl(u_, gb_ + 5);             \
    wx_[0] = __shfl(u_, gb_ + 6); wx_[1] = __shfl(u_, gb_ + 7);             \
    wx_[2] = __shfl(v_, gb_ + 0); wx_[3] = __shfl(v_, gb_ + 1);             \
    wx_[4] = __shfl(v_, gb_ + 2); wx_[5] = __shfl(v_, gb_ + 3);             \
    float accr0 = 0.f, acci0 = 0.f, accr1 = 0.f, acci1 = 0.f;               \
    _Pragma("unroll")                                                       \
    for (int j_ = 0; j_ < 6; ++j_) {                                        \
      _Pragma("unroll")                                                     \
      for (int p_ = 0; p_ < 3; ++p_) {                                      \
        float w_ = wy_[j_] * wx_[2 * p_ + tp];                              \
        uint2v hu_ = __builtin_bit_cast(uint2v, H[j_ * 3 + p_]);            \
        fmamix_lo(accr0, w_, hu_.x); fmamix_hi(acci0, w_, hu_.x);           \
        fmamix_lo(accr1, w_, hu_.y); fmamix_hi(acci1, w_, hu_.y);           \
      }                                                                     \
    }                                                                       \
    accr0 += __shfl_xor(accr0, 4); acci0 += __shfl_xor(acci0, 4);           \
    accr1 += __shfl_xor(accr1, 4); acci1 += __shfl_xor(acci1, 4);           \
    const float s_ = 1.0f / (36.0f * GSCALE);                               \
    float2 res_ = tp ? make_float2(accr1 * s_, acci1 * s_)                  \
                     : make_float2(accr0 * s_, acci0 * s_);                 \
    if ((KIDX) < K) out[(size_t)(2 * cp + tp) * K + (KIDX)] = res_;         \
  }

__global__ __launch_bounds__(256) void interp_kernel(const float* __restrict__ trj,
                                                     const half4* __restrict__ g4,
                                                     float2* __restrict__ out, int K) {
    __shared__ float gtab[1025];   // g(t) = I0(beta*sqrt(1-t)), t = u^2
    for (int i = threadIdx.x; i < 1025; i += 256)
        gtab[i] = i0f(BETA_F * sqrtf(1.0f - (float)i * (1.0f / 1024.0f)));
    __syncthreads();

    const float2* trj2 = (const float2*)trj;
    int grp = threadIdx.x >> 3;    // 8-lane point group (0..31)
    int c   = threadIdx.x & 7;     // lane role
    int cp  = c & 3;               // coil pair (coils 2cp, 2cp+1)
    int tp  = c >> 2;              // tap parity (0: l=0,2,4; 1: l=1,3,5)
    int kb  = blockIdx.x * (32 * PPT) + grp;

    half4 hA[18], hB[18];
    float2 tjA, tjB;
    ISSUE(kb, tjA, hA)
    #pragma unroll
    for (int it = 0; it < PPT; ++it) {
        int k = kb + it * 32;
        if ((it & 1) == 0) {
            if (it + 1 < PPT) ISSUE(kb + (it + 1) * 32, tjB, hB)
            CONSUME(tjA, hA, k)
        } else {
            if (it + 1 < PPT) ISSUE(kb + (it + 1) * 32, tjA, hA)
            CONSUME(tjB, hB, k)
        }
    }
}

extern "C" void kernel_launch(void* const* d_in, const int* in_sizes, int n_in,
                              void* d_out, int out_size, void* d_ws, size_t ws_size,
                              hipStream_t stream) {
    const float* imr = (const float*)d_in[0];
    const float* imi = (const float*)d_in[1];
    const float* trj = (const float*)d_in[2];
    int K = in_sizes[2] / 2;

    float2* buf1  = (float2*)d_ws;                             // [kx][y][coil] 6.55 MB
    half4*  gridh = (half4*)(buf1 + (size_t)OS * OS * NCOIL);  // fp16 grid 3.28 MB

    (void)n_in; (void)out_size; (void)ws_size;

    dft_pass1<<<IMN, 320, 0, stream>>>(imr, imi, buf1);
    dft_pass2<<<OS, 320, 0, stream>>>(buf1, (half8*)gridh);
    int nblk = (K + 32 * PPT - 1) / (32 * PPT);
    interp_kernel<<<nblk, 256, 0, stream>>>(trj, gridh, (float2*)d_out, K);
}

// Round 7
// 207.415 us; speedup vs baseline: 1.0470x; 1.0470x over previous
//
#include <hip/hip_runtime.h>
#include <math.h>

#define OS    320      // oversampled grid (ceil(1.25*256))
#define IMN   256
#define NCOIL 8
#define PI_F  3.14159265358979f
#define BETA_F 10.955108f   // pi*sqrt((4.8*0.75)^2 - 0.8)
#define GSCALE 65536.0f     // fp16 grid scaling

typedef _Float16 half8  __attribute__((ext_vector_type(8)));
typedef _Float16 half4  __attribute__((ext_vector_type(4)));
typedef _Float16 half2v __attribute__((ext_vector_type(2)));

// ---- Kaiser-Bessel kernel: exact A&S I0 polynomial (matches reference) ----
__device__ __forceinline__ float i0f(float x) {
    if (x < 3.75f) {
        float y = x * (1.0f / 3.75f); y *= y;
        return 1.0f + y*(3.5156229f + y*(3.0899424f + y*(1.2067492f
             + y*(0.2659732f + y*(0.0360768f + y*0.0045813f)))));
    } else {
        float t = 3.75f / x;
        float p = 0.39894228f + t*(0.01328592f + t*(0.00225319f + t*(-0.00157565f
              + t*(0.00916281f + t*(-0.02057706f + t*(0.02635537f + t*(-0.01647633f
              + t*0.00392377f)))))));
        return expf(x) * rsqrtf(x) * p;
    }
}

__device__ __forceinline__ float kbf(float u) {
    float q = 1.0f - u * u;
    q = fmaxf(q, 0.0f);
    return i0f(BETA_F * sqrtf(q));
}

__device__ __forceinline__ float apod1(int i) {
    float idx = (float)(i - 128);
    float c = PI_F * 6.0f * idx * (1.0f / (float)OS);
    float a = sqrtf(BETA_F * BETA_F - c * c);
    float sh = 0.5f * (expf(a) - expf(-a));
    return a / sh;
}

// ---- K1: fused apod + pad + DFT along x.  Block = image row iy (0..255).
// 640 threads: halves t<320 (m=0..127) and t>=320 (m=128..255) each compute
// a 128-term partial; upper half deposits partials in LDS, lower combines.
// out: [kx][y][coil] float2.
__global__ __launch_bounds__(640) void dft_pass1(const float* __restrict__ imr,
                                                 const float* __restrict__ imi,
                                                 float2* __restrict__ out) {
    __shared__ float2 xs[IMN * NCOIL];        // apodized row, 16 KB
    __shared__ float2 ps[OS * 9];             // upper-half partials (pad 9)
    int iy = blockIdx.x;
    int t  = threadIdx.x;
    int half = (t >= OS) ? 1 : 0;
    int tt = half ? t - OS : t;               // kx
    if (t < IMN) {
        float ap = apod1(t);
        int base = iy * IMN + t;
        #pragma unroll
        for (int b = 0; b < 8; ++b) {
            float xr = imr[b * (IMN * IMN) + base];   // coalesced per coil
            float xi = imi[b * (IMN * IMN) + base];
            xs[t * 8 + b] = make_float2(xr * ap, xi * ap);
        }
    }
    __syncthreads();

    float ar[8], ai[8];
    #pragma unroll
    for (int b = 0; b < 8; ++b) { ar[b] = 0.f; ai[b] = 0.f; }
    float ang_t = (float)tt * (-2.0f * PI_F / (float)OS);
    float wsr = cosf(ang_t), wsi = sinf(ang_t);
    // n = (m+192)%320: half0 n=192..319, half1 n=0..127 (no wraps inside)
    int m0  = half ? 128 : 0;
    int idx = half ? 0 : (tt * 192) % 320;    // (tt*n) mod 320 at m=m0
    float wr = 1.f, wi = 0.f;
    const float4* xv = (const float4*)xs;
    #pragma unroll 16
    for (int mm = 0; mm < 128; ++mm) {
        if ((mm & 15) == 0) {                 // exact twiddle refresh
            float ang = (float)idx * (-2.0f * PI_F / (float)OS);
            wr = cosf(ang); wi = sinf(ang);
        }
        const float4* xp = xv + (m0 + mm) * 4;
        #pragma unroll
        for (int q = 0; q < 4; ++q) {
            float4 x = xp[q];                 // coils 2q, 2q+1 (LDS broadcast)
            ar[2*q]   = fmaf(x.x, wr, fmaf(-x.y, wi, ar[2*q]));
            ai[2*q]   = fmaf(x.x, wi, fmaf( x.y, wr, ai[2*q]));
            ar[2*q+1] = fmaf(x.z, wr, fmaf(-x.w, wi, ar[2*q+1]));
            ai[2*q+1] = fmaf(x.z, wi, fmaf( x.w, wr, ai[2*q+1]));
        }
        float nwr = fmaf(wr, wsr, -wi * wsi);
        float nwi = fmaf(wr, wsi,  wi * wsr);
        wr = nwr; wi = nwi;
        idx += tt; if (idx >= OS) idx -= OS;
    }
    if (half) {
        #pragma unroll
        for (int b = 0; b < 8; ++b) ps[tt * 9 + b] = make_float2(ar[b], ai[b]);
    }
    __syncthreads();
    if (!half) {
        #pragma unroll
        for (int b = 0; b < 8; ++b) {
            float2 p = ps[tt * 9 + b];
            ar[b] += p.x; ai[b] += p.y;
        }
        float ay = apod1(iy) * (1.0f / 256.0f);   // y-apod + /sqrt(ny*nx)
        int y = iy + 192; if (y >= OS) y -= OS;
        float4* op = (float4*)(out + ((size_t)tt * OS + y) * NCOIL);
        #pragma unroll
        for (int q = 0; q < 4; ++q)
            op[q] = make_float4(ar[2*q] * ay, ai[2*q] * ay,
                                ar[2*q+1] * ay, ai[2*q+1] * ay);
    }
}

// ---- K2: DFT along y, same 640-thread split; fp16 grid out, fftshift folded
// in: [kx][y][coil] float2 (only y=(m+192)%320 rows valid).
// out: fp16 [(tt+160)%320][(kx+160)%320][coil], scaled by GSCALE.
__global__ __launch_bounds__(640) void dft_pass2(const float2* __restrict__ in,
                                                 half8* __restrict__ outg) {
    __shared__ float2 xs[IMN * NCOIL];
    __shared__ float2 ps[OS * 9];
    int kx = blockIdx.x;
    int t  = threadIdx.x;
    int half = (t >= OS) ? 1 : 0;
    int tt = half ? t - OS : t;
    const float2* row = in + (size_t)kx * OS * NCOIL;
    for (int i = t; i < IMN * NCOIL; i += 640) {
        int m = i >> 3, b = i & 7;
        int n = m + 192; if (n >= OS) n -= OS;
        xs[i] = row[n * NCOIL + b];
    }
    __syncthreads();

    float ar[8], ai[8];
    #pragma unroll
    for (int b = 0; b < 8; ++b) { ar[b] = 0.f; ai[b] = 0.f; }
    float ang_t = (float)tt * (-2.0f * PI_F / (float)OS);
    float wsr = cosf(ang_t), wsi = sinf(ang_t);
    int m0  = half ? 128 : 0;
    int idx = half ? 0 : (tt * 192) % 320;
    float wr = 1.f, wi = 0.f;
    const float4* xv = (const float4*)xs;
    #pragma unroll 16
    for (int mm = 0; mm < 128; ++mm) {
        if ((mm & 15) == 0) {
            float ang = (float)idx * (-2.0f * PI_F / (float)OS);
            wr = cosf(ang); wi = sinf(ang);
        }
        const float4* xp = xv + (m0 + mm) * 4;
        #pragma unroll
        for (int q = 0; q < 4; ++q) {
            float4 x = xp[q];
            ar[2*q]   = fmaf(x.x, wr, fmaf(-x.y, wi, ar[2*q]));
            ai[2*q]   = fmaf(x.x, wi, fmaf( x.y, wr, ai[2*q]));
            ar[2*q+1] = fmaf(x.z, wr, fmaf(-x.w, wi, ar[2*q+1]));
            ai[2*q+1] = fmaf(x.z, wi, fmaf( x.w, wr, ai[2*q+1]));
        }
        float nwr = fmaf(wr, wsr, -wi * wsi);
        float nwi = fmaf(wr, wsi,  wi * wsr);
        wr = nwr; wi = nwi;
        idx += tt; if (idx >= OS) idx -= OS;
    }
    if (half) {
        #pragma unroll
        for (int b = 0; b < 8; ++b) ps[tt * 9 + b] = make_float2(ar[b], ai[b]);
    }
    __syncthreads();
    if (!half) {
        #pragma unroll
        for (int b = 0; b < 8; ++b) {
            float2 p = ps[tt * 9 + b];
            ar[b] += p.x; ai[b] += p.y;
        }
        int r = tt + 160; if (r >= OS) r -= OS;   // fftshift fold (rows)
        int c = kx + 160; if (c >= OS) c -= OS;   // fftshift fold (cols)
        half8 h0, h1;
        #pragma unroll
        for (int q = 0; q < 4; ++q) {
            h0[2*q]   = (_Float16)(ar[q] * GSCALE);
            h0[2*q+1] = (_Float16)(ai[q] * GSCALE);
            h1[2*q]   = (_Float16)(ar[q+4] * GSCALE);
            h1[2*q+1] = (_Float16)(ai[q+4] * GSCALE);
        }
        half8* gp = outg + ((size_t)r * OS + c) * 2;
        gp[0] = h0; gp[1] = h1;
    }
}

// ---- K3: KB 6x6 gather; 8 lanes/point = 4 coil-pairs x 2 tap-parities.
// Nontemporal output stores / trj loads keep the fp16 grid L2-resident.
__global__ __launch_bounds__(256) void interp_kernel(const float* __restrict__ trj,
                                                     const half4* __restrict__ g4,
                                                     float2* __restrict__ out, int K) {
    int tid = blockIdx.x * 256 + threadIdx.x;
    int k = tid >> 3;          // point index
    int c = tid & 7;           // lane role
    int cp = c & 3;            // coil pair (coils 2cp, 2cp+1)
    int tp = c >> 2;           // tap parity (0: l=0,2,4; 1: l=1,3,5)
    if (k >= K) return;
    double td = __builtin_nontemporal_load((const double*)trj + k);
    union { double d; float2 f; } tu; tu.d = td;
    float ty = tu.f.x, tx = tu.f.y;
    float cy = ty * 1.25f + 160.0f;   // in [0, 320)
    float cx = tx * 1.25f + 160.0f;
    int y0 = (int)ceilf(cy - 3.0f);   // in [-3, 317]
    int x0 = (int)ceilf(cx - 3.0f);

    int rowoff[6], coloff[6];
    #pragma unroll
    for (int j = 0; j < 6; ++j) {
        int yy = y0 + j; if (yy < 0) yy += OS; if (yy >= OS) yy -= OS;
        rowoff[j] = yy * (OS * 4);    // half4 units: cell = 4 half4
        int xx = x0 + j; if (xx < 0) xx += OS; if (xx >= OS) xx -= OS;
        coloff[j] = xx * 4;
    }

    // issue all 18 paired-tap gathers (8B/lane; x-pairs share 64B lines)
    half4 h[18];
    #pragma unroll
    for (int j = 0; j < 6; ++j)
        #pragma unroll
        for (int p = 0; p < 3; ++p)
            h[j * 3 + p] = g4[rowoff[j] + coloff[2 * p + tp] + cp];

    // 12 KB weights per point: 2 kbf evals per lane, distribute via shfl
    float argu = (c < 6) ? ((float)(y0 + c) - cy) * (1.0f / 3.0f)
                         : ((float)(x0 + (c - 6)) - cx) * (1.0f / 3.0f);
    float u = kbf(argu);
    float argv = ((float)(x0 + 2 + (c & 3)) - cx) * (1.0f / 3.0f);
    float v = kbf(argv);
    int lane = threadIdx.x & 63;
    int gb = lane & 56;               // 8-lane group base within wave
    float wy0 = __shfl(u, gb + 0), wy1 = __shfl(u, gb + 1), wy2 = __shfl(u, gb + 2);
    float wy3 = __shfl(u, gb + 3), wy4 = __shfl(u, gb + 4), wy5 = __shfl(u, gb + 5);
    float wx0 = __shfl(u, gb + 6), wx1 = __shfl(u, gb + 7);
    float wx2 = __shfl(v, gb + 0), wx3 = __shfl(v, gb + 1);
    float wx4 = __shfl(v, gb + 2), wx5 = __shfl(v, gb + 3);
    float wy[6] = {wy0, wy1, wy2, wy3, wy4, wy5};
    float wx[6] = {wx0, wx1, wx2, wx3, wx4, wx5};

    float accr0 = 0.f, acci0 = 0.f, accr1 = 0.f, acci1 = 0.f;
    #pragma unroll
    for (int j = 0; j < 6; ++j) {
        float wyj = wy[j];
        #pragma unroll
        for (int p = 0; p < 3; ++p) {
            float w = wyj * wx[2 * p + tp];
            half4 hv = h[j * 3 + p];
            accr0 = fmaf(w, (float)hv[0], accr0);
            acci0 = fmaf(w, (float)hv[1], acci0);
            accr1 = fmaf(w, (float)hv[2], accr1);
            acci1 = fmaf(w, (float)hv[3], acci1);
        }
    }
    // merge tap parities (lane c <-> c^4)
    accr0 += __shfl_xor(accr0, 4);
    acci0 += __shfl_xor(acci0, 4);
    accr1 += __shfl_xor(accr1, 4);
    acci1 += __shfl_xor(acci1, 4);

    const float s = 1.0f / (36.0f * GSCALE);
    float2 res = tp ? make_float2(accr1 * s, acci1 * s)
                    : make_float2(accr0 * s, acci0 * s);
    union { float2 f; double d; } ru; ru.f = res;
    __builtin_nontemporal_store(ru.d,
        (double*)(out + (size_t)(2 * cp + tp) * K + k));   // bypass L2
}

extern "C" void kernel_launch(void* const* d_in, const int* in_sizes, int n_in,
                              void* d_out, int out_size, void* d_ws, size_t ws_size,
                              hipStream_t stream) {
    const float* imr = (const float*)d_in[0];
    const float* imi = (const float*)d_in[1];
    const float* trj = (const float*)d_in[2];
    int K = in_sizes[2] / 2;

    float2* buf1  = (float2*)d_ws;                             // [kx][y][coil] 6.55 MB
    half4*  gridh = (half4*)(buf1 + (size_t)OS * OS * NCOIL);  // fp16 grid 3.28 MB

    (void)n_in; (void)out_size; (void)ws_size;

    dft_pass1<<<IMN, 640, 0, stream>>>(imr, imi, buf1);
    dft_pass2<<<OS, 640, 0, stream>>>(buf1, (half8*)gridh);
    interp_kernel<<<(K * NCOIL + 255) / 256, 256, 0, stream>>>(trj, gridh,
                                                               (float2*)d_out, K);
}

// Round 8
// 200.408 us; speedup vs baseline: 1.0836x; 1.0350x over previous
//
#include <hip/hip_runtime.h>
#include <math.h>

#define OS    320      // oversampled grid (ceil(1.25*256))
#define IMN   256
#define NCOIL 8
#define HS    326      // halo grid dim (3-cell wrap halo each side)
#define HROWB (HS * 32)   // halo row stride in bytes (cell = 32B)
#define PI_F  3.14159265358979f
#define BETA_F 10.955108f   // pi*sqrt((4.8*0.75)^2 - 0.8)
#define GSCALE 65536.0f     // fp16 grid scaling

typedef _Float16 half8  __attribute__((ext_vector_type(8)));
typedef _Float16 half4  __attribute__((ext_vector_type(4)));
typedef unsigned uint2v __attribute__((ext_vector_type(2)));

// f32 acc += f32 w * f16 (lo/hi half of dword h)   [validated r6]
__device__ __forceinline__ void fmamix_lo(float& acc, float w, unsigned h) {
    asm("v_fma_mix_f32 %0, %1, %2, %0 op_sel_hi:[0,1,0]"
        : "+v"(acc) : "v"(w), "v"(h));
}
__device__ __forceinline__ void fmamix_hi(float& acc, float w, unsigned h) {
    asm("v_fma_mix_f32 %0, %1, %2, %0 op_sel:[0,1,0] op_sel_hi:[0,1,0]"
        : "+v"(acc) : "v"(w), "v"(h));
}

// ---- Kaiser-Bessel: exact A&S I0 polynomial (matches reference) ----
__device__ __forceinline__ float i0f(float x) {
    if (x < 3.75f) {
        float y = x * (1.0f / 3.75f); y *= y;
        return 1.0f + y*(3.5156229f + y*(3.0899424f + y*(1.2067492f
             + y*(0.2659732f + y*(0.0360768f + y*0.0045813f)))));
    } else {
        float t = 3.75f / x;
        float p = 0.39894228f + t*(0.01328592f + t*(0.00225319f + t*(-0.00157565f
              + t*(0.00916281f + t*(-0.02057706f + t*(0.02635537f + t*(-0.01647633f
              + t*0.00392377f)))))));
        return expf(x) * rsqrtf(x) * p;
    }
}

__device__ __forceinline__ float apod1(int i) {
    float idx = (float)(i - 128);
    float c = PI_F * 6.0f * idx * (1.0f / (float)OS);
    float a = sqrtf(BETA_F * BETA_F - c * c);
    float sh = 0.5f * (expf(a) - expf(-a));
    return a / sh;
}

// ---- K0: weight LUT  g[i] = I0(beta*sqrt(1 - i/1024)), i=0..1024 ----
__global__ void build_lut(float* __restrict__ lut) {
    int i = blockIdx.x * 256 + threadIdx.x;
    if (i <= 1024)
        lut[i] = i0f(BETA_F * sqrtf(1.0f - (float)i * (1.0f / 1024.0f)));
}

// ---- K1: fused apod + pad + DFT along x.  Block = (row iy, coil group cg).
// 4 coils per block (coil-split doubles CU parallelism, no combine needed).
// out: [kx][y][coil] float2.
__global__ __launch_bounds__(320) void dft_pass1(const float* __restrict__ imr,
                                                 const float* __restrict__ imi,
                                                 float2* __restrict__ out) {
    __shared__ float2 xs[IMN * 4];       // [m][coil-in-group], 8 KB
    int iy = blockIdx.x;
    int c0 = blockIdx.y * 4;
    int t  = threadIdx.x;                // kx
    if (t < IMN) {
        float ap = apod1(t);
        int base = iy * IMN + t;
        #pragma unroll
        for (int b = 0; b < 4; ++b) {
            float xr = imr[(c0 + b) * (IMN * IMN) + base];   // coalesced
            float xi = imi[(c0 + b) * (IMN * IMN) + base];
            xs[t * 4 + b] = make_float2(xr * ap, xi * ap);
        }
    }
    __syncthreads();

    float ar[4], ai[4];
    #pragma unroll
    for (int b = 0; b < 4; ++b) { ar[b] = 0.f; ai[b] = 0.f; }
    float ang_t = (float)t * (-2.0f * PI_F / (float)OS);
    float wsr = cosf(ang_t), wsi = sinf(ang_t);
    int idx = (t * 192) % 320;            // (t*n) mod 320 at n=192
    float wr = 1.f, wi = 0.f;
    const float4* xv = (const float4*)xs;
    #pragma unroll 16
    for (int m = 0; m < 256; ++m) {
        if ((m & 15) == 0) {              // exact twiddle refresh
            float ang = (float)idx * (-2.0f * PI_F / (float)OS);
            wr = cosf(ang); wi = sinf(ang);
        }
        const float4* xp = xv + m * 2;
        #pragma unroll
        for (int q = 0; q < 2; ++q) {
            float4 x = xp[q];             // coils 2q, 2q+1 (LDS broadcast)
            ar[2*q]   = fmaf(x.x, wr, fmaf(-x.y, wi, ar[2*q]));
            ai[2*q]   = fmaf(x.x, wi, fmaf( x.y, wr, ai[2*q]));
            ar[2*q+1] = fmaf(x.z, wr, fmaf(-x.w, wi, ar[2*q+1]));
            ai[2*q+1] = fmaf(x.z, wi, fmaf( x.w, wr, ai[2*q+1]));
        }
        float nwr = fmaf(wr, wsr, -wi * wsi);
        float nwi = fmaf(wr, wsi,  wi * wsr);
        wr = nwr; wi = nwi;
        idx += t; if (idx >= OS) idx -= OS;
    }
    float ay = apod1(iy) * (1.0f / 256.0f);   // y-apod + /sqrt(ny*nx)
    int y = iy + 192; if (y >= OS) y -= OS;
    float4* op = (float4*)(out + ((size_t)t * OS + y) * NCOIL + c0);
    op[0] = make_float4(ar[0] * ay, ai[0] * ay, ar[1] * ay, ai[1] * ay);
    op[1] = make_float4(ar[2] * ay, ai[2] * ay, ar[3] * ay, ai[3] * ay);
}

// ---- K2: DFT along y (coil-split); writes fp16 HALO grid, fftshift folded.
// Halo cell (hy,hx) holds logical grid[(hy-3)%320][(hx-3)%320]; edge rows/cols
// replicated so interp needs no wrap logic.
__global__ __launch_bounds__(320) void dft_pass2(const float2* __restrict__ in,
                                                 char* __restrict__ gbytes) {
    __shared__ float2 xs[IMN * 4];
    int kx = blockIdx.x;
    int c0 = blockIdx.y * 4;
    int t  = threadIdx.x;
    const float2* row = in + (size_t)kx * OS * NCOIL + c0;
    for (int i = t; i < IMN * 4; i += 320) {
        int m = i >> 2, b = i & 3;
        int n = m + 192; if (n >= OS) n -= OS;
        xs[i] = row[n * NCOIL + b];
    }
    __syncthreads();

    float ar[4], ai[4];
    #pragma unroll
    for (int b = 0; b < 4; ++b) { ar[b] = 0.f; ai[b] = 0.f; }
    float ang_t = (float)t * (-2.0f * PI_F / (float)OS);
    float wsr = cosf(ang_t), wsi = sinf(ang_t);
    int idx = (t * 192) % 320;
    float wr = 1.f, wi = 0.f;
    const float4* xv = (const float4*)xs;
    #pragma unroll 16
    for (int m = 0; m < 256; ++m) {
        if ((m & 15) == 0) {
            float ang = (float)idx * (-2.0f * PI_F / (float)OS);
            wr = cosf(ang); wi = sinf(ang);
        }
        const float4* xp = xv + m * 2;
        #pragma unroll
        for (int q = 0; q < 2; ++q) {
            float4 x = xp[q];
            ar[2*q]   = fmaf(x.x, wr, fmaf(-x.y, wi, ar[2*q]));
            ai[2*q]   = fmaf(x.x, wi, fmaf( x.y, wr, ai[2*q]));
            ar[2*q+1] = fmaf(x.z, wr, fmaf(-x.w, wi, ar[2*q+1]));
            ai[2*q+1] = fmaf(x.z, wi, fmaf( x.w, wr, ai[2*q+1]));
        }
        float nwr = fmaf(wr, wsr, -wi * wsi);
        float nwi = fmaf(wr, wsi,  wi * wsr);
        wr = nwr; wi = nwi;
        idx += t; if (idx >= OS) idx -= OS;
    }
    int r = t + 160;  if (r >= OS) r -= OS;   // fftshift fold (rows)
    int c = kx + 160; if (c >= OS) c -= OS;   // fftshift fold (cols)
    half8 hh;
    #pragma unroll
    for (int q = 0; q < 4; ++q) {
        hh[2*q]   = (_Float16)(ar[q] * GSCALE);
        hh[2*q+1] = (_Float16)(ai[q] * GSCALE);
    }
    // replicate to all halo images of (r,c): hy in {r+3, r+323 (r<3), r-317 (r>=317)}
    int hys[2]; int nhy = 1; hys[0] = r + 3;
    if (r < 3)        hys[nhy++] = r + 323;
    else if (r >= 317) hys[nhy++] = r - 317;
    int hxs[2]; int nhx = 1; hxs[0] = c + 3;
    if (c < 3)        hxs[nhx++] = c + 323;
    else if (c >= 317) hxs[nhx++] = c - 317;
    for (int a = 0; a < nhy; ++a)
        for (int b = 0; b < nhx; ++b)
            *(half8*)(gbytes + (size_t)hys[a] * HROWB + hxs[b] * 32 + c0 * 4) = hh;
}

// ---- K3: KB 6x6 gather on halo grid; 8 lanes/point = 4 coil-pairs x 2
// tap-parities; 6 row bases + immediate offsets (no wrap logic); weights via
// L1-resident global LUT + lerp; fma_mix accumulate (no f16->f32 cvts).
__global__ __launch_bounds__(256) void interp_kernel(const float* __restrict__ trj,
                                                     const char* __restrict__ gbytes,
                                                     const float* __restrict__ lut,
                                                     float2* __restrict__ out, int K) {
    int tid = blockIdx.x * 256 + threadIdx.x;
    int k = tid >> 3;          // point index
    int c = tid & 7;           // lane role
    int cp = c & 3;            // coil pair (coils 2cp, 2cp+1)
    int tp = c >> 2;           // tap parity (0: l=0,2,4; 1: l=1,3,5)
    if (k >= K) return;
    float2 tj = ((const float2*)trj)[k];
    float cy = tj.x * 1.25f + 160.0f;   // in [0, 320)
    float cx = tj.y * 1.25f + 160.0f;
    int y0 = (int)ceilf(cy - 3.0f);     // in [-3, 317]
    int x0 = (int)ceilf(cx - 3.0f);

    // one base address per tap row; columns advance by compile-time imms
    const char* base0 = gbytes + (size_t)(y0 + 3) * HROWB
                      + (x0 + 3) * 32 + cp * 8 + tp * 32;

    half4 h[18];
    #pragma unroll
    for (int j = 0; j < 6; ++j) {
        const char* rb = base0 + j * HROWB;
        #pragma unroll
        for (int p = 0; p < 3; ++p)
            h[j * 3 + p] = *(const half4*)(rb + p * 64);
    }

    // 12 weights per point: 2 LUT lookups per lane, distribute via shfl
    float argu = (c < 6) ? ((float)(y0 + c) - cy) * (1.0f / 3.0f)
                         : ((float)(x0 + (c - 6)) - cx) * (1.0f / 3.0f);
    float argv = ((float)(x0 + 2 + cp) - cx) * (1.0f / 3.0f);
    float tu = fminf(argu * argu * 1024.0f, 1023.0f);
    int   iu = (int)tu;  float fu = tu - (float)iu;
    float a0 = lut[iu], a1 = lut[iu + 1];
    float u = fmaf(fu, a1 - a0, a0);
    float tv = fminf(argv * argv * 1024.0f, 1023.0f);
    int   iv = (int)tv;  float fv = tv - (float)iv;
    float b0 = lut[iv], b1 = lut[iv + 1];
    float v = fmaf(fv, b1 - b0, b0);

    int gb = (threadIdx.x & 63) & 56;   // 8-lane group base within wave
    float wy[6], wx[6];
    wy[0] = __shfl(u, gb + 0); wy[1] = __shfl(u, gb + 1);
    wy[2] = __shfl(u, gb + 2); wy[3] = __shfl(u, gb + 3);
    wy[4] = __shfl(u, gb + 4); wy[5] = __shfl(u, gb + 5);
    wx[0] = __shfl(u, gb + 6); wx[1] = __shfl(u, gb + 7);
    wx[2] = __shfl(v, gb + 0); wx[3] = __shfl(v, gb + 1);
    wx[4] = __shfl(v, gb + 2); wx[5] = __shfl(v, gb + 3);

    float accr0 = 0.f, acci0 = 0.f, accr1 = 0.f, acci1 = 0.f;
    #pragma unroll
    for (int j = 0; j < 6; ++j) {
        float wyj = wy[j];
        #pragma unroll
        for (int p = 0; p < 3; ++p) {
            float w = wyj * wx[2 * p + tp];
            uint2v hu = __builtin_bit_cast(uint2v, h[j * 3 + p]);
            fmamix_lo(accr0, w, hu.x);   // coil 2cp   re
            fmamix_hi(acci0, w, hu.x);   //            im
            fmamix_lo(accr1, w, hu.y);   // coil 2cp+1 re
            fmamix_hi(acci1, w, hu.y);
        }
    }
    // merge tap parities (lane c <-> c^4)
    accr0 += __shfl_xor(accr0, 4);
    acci0 += __shfl_xor(acci0, 4);
    accr1 += __shfl_xor(accr1, 4);
    acci1 += __shfl_xor(acci1, 4);

    const float s = 1.0f / (36.0f * GSCALE);
    float2 res = tp ? make_float2(accr1 * s, acci1 * s)
                    : make_float2(accr0 * s, acci0 * s);
    union { float2 f; double d; } ru; ru.f = res;
    __builtin_nontemporal_store(ru.d,
        (double*)(out + (size_t)(2 * cp + tp) * K + k));   // bypass L2
}

extern "C" void kernel_launch(void* const* d_in, const int* in_sizes, int n_in,
                              void* d_out, int out_size, void* d_ws, size_t ws_size,
                              hipStream_t stream) {
    const float* imr = (const float*)d_in[0];
    const float* imi = (const float*)d_in[1];
    const float* trj = (const float*)d_in[2];
    int K = in_sizes[2] / 2;

    char* ws = (char*)d_ws;
    float2* buf1   = (float2*)ws;                       // [kx][y][coil] 6.55 MB
    char*   gridh  = ws + (size_t)OS * OS * NCOIL * 8;  // halo fp16 grid 3.40 MB
    float*  lut    = (float*)(gridh + (size_t)HS * HS * 32);  // 4.1 KB

    (void)n_in; (void)out_size; (void)ws_size;

    build_lut<<<5, 256, 0, stream>>>(lut);
    dft_pass1<<<dim3(IMN, 2), 320, 0, stream>>>(imr, imi, buf1);
    dft_pass2<<<dim3(OS, 2), 320, 0, stream>>>(buf1, gridh);
    interp_kernel<<<(K * NCOIL + 255) / 256, 256, 0, stream>>>(trj, gridh, lut,
                                                               (float2*)d_out, K);
}